// Round 4
// baseline (117.353 us; speedup 1.0000x reference)
//
#include <hip/hip_runtime.h>
#include <hip/hip_bf16.h>

// TT embedding, fully fused single kernel.
//   core0: (1, 8, 40, 16)   [x, p, b]   strides x:640 p:16 b:1
//   core1: (16, 8, 32, 16)  [b, y, q, c] strides b:4096 y:512 q:16 c:1
//   core2: (16, 16, 25, 1)  [c, z, r]   strides c:400 z:25 r:1
// out[t, (x*8+y)*16+z], id v -> p=v/800, q=(v/25)%32, r=v%25
//
// Per token (one wave): build E[c][xy] = sum_b core0[x,p,b]*core1[b,y,q,c]
// into per-wave LDS (lane owns 2 (y,c) pairs; B1 cols from L2-resident core1;
// A0 via wave-uniform scalar loads), then contract out[xy,z] =
// sum_c E[c][xy]*C2T[r][c][z] with C2T block-staged in LDS.
// No T12 workspace, no precompute dispatch — one launch total.

typedef float v4f __attribute__((ext_vector_type(4)));

__global__ __launch_bounds__(512) void tt_fused_kernel(
    const float* __restrict__ core0, const float* __restrict__ core1,
    const float* __restrict__ core2, const int* __restrict__ ids,
    float* __restrict__ out) {
  __shared__ __align__(16) float sC2T[25 * 256];  // [r][c][z], 25.6 KB
  __shared__ __align__(16) float sE[8 * 1088];    // per-wave E[c][xy], stride 68

  // stage transposed core2: sC2T[r*256 + c*16 + z] = core2[(c*16+z)*25 + r]
  for (int i = threadIdx.x; i < 6400; i += 512) {
    int r = i >> 8, cz = i & 255;
    sC2T[i] = core2[cz * 25 + r];
  }
  __syncthreads();

  const int wave = threadIdx.x >> 6;
  const int lane = threadIdx.x & 63;
  float* __restrict__ Ew = sE + wave * 1088;

  const int ey = lane & 7;    // E-build: owned y
  const int ec0 = lane >> 3;  // E-build: owned c (pair0; +8 for pair1)
  const int xyg = lane >> 2;  // contraction: xy quad (0..15)
  const int zg = lane & 3;    // contraction: z quad (0..3)

  const int tbase = (blockIdx.x * 8 + wave) * 2;  // 1024 blocks * 8 waves * 2 tok

  for (int k = 0; k < 2; ++k) {
    const int t = tbase + k;
    int id = ids[t];  // t wave-uniform -> scalar load
    int p = __builtin_amdgcn_readfirstlane(id / 800);
    int rem = id - p * 800;
    int q = __builtin_amdgcn_readfirstlane(rem / 25);
    int r = __builtin_amdgcn_readfirstlane(rem - q * 25);

    const float* __restrict__ A0 = core0 + p * 16;  // A0[x*640 + b], uniform
    const float* __restrict__ B1 = core1 + q * 16 + ey * 512 + ec0;

    // E-build: lane computes E[c][x*8+ey] for its 2 c's, all 8 x
#pragma unroll
    for (int pp = 0; pp < 2; ++pp) {
      float bcol[16];
#pragma unroll
      for (int b = 0; b < 16; ++b) bcol[b] = B1[b * 4096 + pp * 8];  // L2-hot
      const int c = ec0 + pp * 8;
#pragma unroll
      for (int x = 0; x < 8; ++x) {
        float acc = 0.f;
#pragma unroll
        for (int b = 0; b < 16; ++b) acc += A0[x * 640 + b] * bcol[b];
        Ew[c * 68 + x * 8 + ey] = acc;  // stride 68: ~2-way banks, 16B-aligned rows
      }
    }
    __syncthreads();  // E visible to all lanes (and orders LDS RAW)

    float acc[4][4];
#pragma unroll
    for (int i = 0; i < 4; ++i)
#pragma unroll
      for (int j = 0; j < 4; ++j) acc[i][j] = 0.f;

    const float* Cr = sC2T + r * 256;
#pragma unroll
    for (int c = 0; c < 16; ++c) {
      v4f e4 = *(const v4f*)(Ew + c * 68 + xyg * 4);  // ds_read_b128
      v4f c4 = *(const v4f*)(Cr + c * 16 + zg * 4);   // 16-way broadcast
#pragma unroll
      for (int i = 0; i < 4; ++i)
#pragma unroll
        for (int j = 0; j < 4; ++j) acc[i][j] += e4[i] * c4[j];
    }

    // out[t*1024 + (xyg*4+i)*16 + zg*4+j], nontemporal stream
    float* dst = out + (size_t)t * 1024 + xyg * 64 + zg * 4;
#pragma unroll
    for (int i = 0; i < 4; ++i) {
      v4f v = {acc[i][0], acc[i][1], acc[i][2], acc[i][3]};
      __builtin_nontemporal_store(v, (v4f*)(dst + i * 16));
    }
    __syncthreads();  // WAR: next token rewrites Ew
  }
}

extern "C" void kernel_launch(void* const* d_in, const int* in_sizes, int n_in,
                              void* d_out, int out_size, void* d_ws, size_t ws_size,
                              hipStream_t stream) {
  const float* core0 = (const float*)d_in[0];
  const float* core1 = (const float*)d_in[1];
  const float* core2 = (const float*)d_in[2];
  const int* ids = (const int*)d_in[3];
  float* out = (float*)d_out;

  // 16384 tokens = 1024 blocks * 8 waves * 2 tokens; d_ws unused
  tt_fused_kernel<<<dim3(1024), dim3(512), 0, stream>>>(core0, core1, core2, ids, out);
}

// Round 5
// 111.821 us; speedup vs baseline: 1.0495x; 1.0495x over previous
//
#include <hip/hip_runtime.h>
#include <hip/hip_bf16.h>

// TT embedding, fully fused single kernel.
//   core0: (1, 8, 40, 16)   [x, p, b]   strides x:640 p:16 b:1
//   core1: (16, 8, 32, 16)  [b, y, q, c] strides b:4096 y:512 q:16 c:1
//   core2: (16, 16, 25, 1)  [c, z, r]   strides c:400 z:25 r:1
// out[t, (x*8+y)*16+z], id v -> p=v/800, q=(v/25)%32, r=v%25
//
// Per token (one wave): build E[c][xy] = sum_b core0[x,p,b]*core1[b,y,q,c]
// into per-wave LDS, then contract out[xy,z] = sum_c E[c][xy]*C2T[r][c][z].
// R5: NO __syncthreads in the token loop — sE is per-wave and CDNA DS ops
// from one wave execute in issue order (lockstep wave), so a compiler-only
// fence (wave_barrier) suffices. 4 tokens/wave, ids/p/q/r preloaded.

typedef float v4f __attribute__((ext_vector_type(4)));

__global__ __launch_bounds__(512) void tt_fused_kernel(
    const float* __restrict__ core0, const float* __restrict__ core1,
    const float* __restrict__ core2, const int* __restrict__ ids,
    float* __restrict__ out) {
  __shared__ __align__(16) float sC2T[25 * 256];  // [r][c][z], 25.6 KB
  __shared__ __align__(16) float sE[8 * 1088];    // per-wave E[c][xy], stride 68

  // stage transposed core2: sC2T[r*256 + c*16 + z] = core2[(c*16+z)*25 + r]
  for (int i = threadIdx.x; i < 6400; i += 512) {
    int r = i >> 8, cz = i & 255;
    sC2T[i] = core2[cz * 25 + r];
  }
  __syncthreads();  // once per block; sC2T is read-only afterwards

  const int wave = threadIdx.x >> 6;
  const int lane = threadIdx.x & 63;
  float* __restrict__ Ew = sE + wave * 1088;

  const int ey = lane & 7;    // E-build: owned y
  const int ec0 = lane >> 3;  // E-build: owned c (pair0; +8 for pair1)
  const int xyg = lane >> 2;  // contraction: xy quad (0..15)
  const int zg = lane & 3;    // contraction: z quad (0..3)

  const int tbase = (blockIdx.x * 8 + wave) * 4;  // 512 blocks * 8 waves * 4 tok

  // preload all 4 ids; t is wave-uniform -> scalar loads, divides hoisted
  int pA[4], qA[4], rA[4];
#pragma unroll
  for (int k = 0; k < 4; ++k) {
    int id = ids[tbase + k];
    int p = __builtin_amdgcn_readfirstlane(id / 800);
    int rem = id - p * 800;
    int q = __builtin_amdgcn_readfirstlane(rem / 25);
    pA[k] = p;
    qA[k] = q;
    rA[k] = __builtin_amdgcn_readfirstlane(rem - q * 25);
  }

#pragma unroll
  for (int k = 0; k < 4; ++k) {
    const int p = pA[k], q = qA[k], r = rA[k];
    const float* __restrict__ A0 = core0 + p * 16;  // wave-uniform -> s_load
    const float* __restrict__ B1 = core1 + q * 16 + ey * 512 + ec0;

    // E-build: lane computes E[c][x*8+ey] for its 2 c's, all 8 x
#pragma unroll
    for (int pp = 0; pp < 2; ++pp) {
      float bcol[16];
#pragma unroll
      for (int b = 0; b < 16; ++b) bcol[b] = B1[b * 4096 + pp * 8];  // L2-hot
      const int c = ec0 + pp * 8;
#pragma unroll
      for (int x = 0; x < 8; ++x) {
        float acc = 0.f;
#pragma unroll
        for (int b = 0; b < 16; ++b) acc += A0[x * 640 + b] * bcol[b];
        Ew[c * 68 + x * 8 + ey] = acc;  // stride 68: <=2-way banks, 16B rows
      }
    }
    // intra-wave LDS RAW: HW DS pipe is in-order per wave; fence the compiler
    __builtin_amdgcn_wave_barrier();
    asm volatile("" ::: "memory");

    float acc[4][4];
#pragma unroll
    for (int i = 0; i < 4; ++i)
#pragma unroll
      for (int j = 0; j < 4; ++j) acc[i][j] = 0.f;

    const float* Cr = sC2T + r * 256;
#pragma unroll
    for (int c = 0; c < 16; ++c) {
      v4f e4 = *(const v4f*)(Ew + c * 68 + xyg * 4);  // ds_read_b128
      v4f c4 = *(const v4f*)(Cr + c * 16 + zg * 4);   // 16-way broadcast
#pragma unroll
      for (int i = 0; i < 4; ++i)
#pragma unroll
        for (int j = 0; j < 4; ++j) acc[i][j] += e4[i] * c4[j];
    }

    // out[t*1024 + (xyg*4+i)*16 + zg*4+j], nontemporal stream (no L2 pollute)
    float* dst = out + (size_t)(tbase + k) * 1024 + xyg * 64 + zg * 4;
#pragma unroll
    for (int i = 0; i < 4; ++i) {
      v4f v = {acc[i][0], acc[i][1], acc[i][2], acc[i][3]};
      __builtin_nontemporal_store(v, (v4f*)(dst + i * 16));
    }
    // WAR: next token rewrites Ew; same-wave in-order DS + compiler fence
    __builtin_amdgcn_wave_barrier();
    asm volatile("" ::: "memory");
  }
}

extern "C" void kernel_launch(void* const* d_in, const int* in_sizes, int n_in,
                              void* d_out, int out_size, void* d_ws, size_t ws_size,
                              hipStream_t stream) {
  const float* core0 = (const float*)d_in[0];
  const float* core1 = (const float*)d_in[1];
  const float* core2 = (const float*)d_in[2];
  const int* ids = (const int*)d_in[3];
  float* out = (float*)d_out;

  // 16384 tokens = 512 blocks * 8 waves * 4 tokens; d_ws unused
  tt_fused_kernel<<<dim3(512), dim3(512), 0, stream>>>(core0, core1, core2, ids, out);
}